// Round 5
// baseline (643.742 us; speedup 1.0000x reference)
//
#include <hip/hip_runtime.h>
#include <hip/hip_fp16.h>
#include <math.h>

#define NB 2048
#define T 200
#define D 64
#define H1 80
#define H2 40
#define NROWS (NB * T)          // 409600
#define EPSV 1e-8f
#define PADV -4294967295.0f

typedef _Float16 f16x8 __attribute__((ext_vector_type(8)));
typedef float f32x4 __attribute__((ext_vector_type(4)));

// ---- workspace layout (byte offsets) ----
#define Z1H_OFF   0ull                  // __half [NROWS*80]  = 65,536,000 B
#define Z2H_OFF   65536000ull           // __half [NROWS*40]  = 32,768,000 B
#define QT_OFF    98304000ull           // float  [NB*80]     =   655,360 B
#define RED1_OFF  98959360ull           // float  [NB*160]    = 1,310,720 B
#define RED2_OFF  100270080ull          // float  [3200*80]   = 1,024,000 B
#define FIN1_OFF  101294080ull          // float  [160]
#define FIN2_OFF  101294720ull          // float  [80]
// total ~96.6 MiB

__device__ __forceinline__ float dice_f(float z, float m, float r, float a) {
  const float xn = (z - m) * r;
  const float p = 1.f / (1.f + expf(-xn));
  return z * (p + a * (1.f - p));
}

// ---------------------------------------------------------------------------
// k0: qt[b,h] = b1[h] + sum_f q[f]*(W1a+W1c)[f][h]   (tiny GEMV)
// ---------------------------------------------------------------------------
__global__ __launch_bounds__(128) void k0_qt(
    const float* __restrict__ qry, const float* __restrict__ W1,
    const float* __restrict__ b1, float* __restrict__ qt)
{
  const int b = blockIdx.x, tid = threadIdx.x;
  __shared__ float qsh[D];
  if (tid < D) qsh[tid] = qry[b * D + tid];
  __syncthreads();
  if (tid < H1) {
    float s = b1[tid];
    #pragma unroll 8
    for (int f = 0; f < D; ++f)
      s += qsh[f] * (W1[f * H1 + tid] + W1[(2 * D + f) * H1 + tid]);
    qt[b * H1 + tid] = s;
  }
}

// ---------------------------------------------------------------------------
// k1: z1 = qt[b] + keys[b] @ Weff[b]  via f16 MFMA (f32 accum).
// Weff built in-kernel (f16 LDS, transposed [h][f]).
// 512 thr = 8 waves; wave -> strips {w, w+8} of 16 rows; 5 n-tiles; K=64 (2 steps).
// ---------------------------------------------------------------------------
__global__ __launch_bounds__(512) void k1_gemm(
    const float* __restrict__ keys, const float* __restrict__ W1,
    const float* __restrict__ qry, const float* __restrict__ qt,
    __half* __restrict__ z1h, float* __restrict__ red1p)
{
  const int b = blockIdx.x, tid = threadIdx.x;
  const int lane = tid & 63, w = tid >> 6;
  __shared__ __align__(16) _Float16 ksh[208][72];   // 29,952 B (A: [t][f])
  __shared__ __align__(16) _Float16 wsh[80][72];    // 11,520 B (B^T: [h][f])
  __shared__ float qsh[D];
  __shared__ float qtsh[H1];
  __shared__ float bsum[H1], bsq[H1];

  if (tid < D) qsh[tid] = qry[b * D + tid];
  if (tid < H1) { qtsh[tid] = qt[b * H1 + tid]; bsum[tid] = 0.f; bsq[tid] = 0.f; }
  __syncthreads();

  // Weff^T[h][f] = W1b - W1c + q[f]*W1d   (coalesced over h)
  for (int idx = tid; idx < D * H1; idx += 512) {
    const int f = idx / H1, h = idx - f * H1;
    const float v = W1[(D + f) * H1 + h] - W1[(2 * D + f) * H1 + h]
                  + qsh[f] * W1[(3 * D + f) * H1 + h];
    wsh[h][f] = (_Float16)v;
  }
  // keys -> f16 LDS
  const float2* ksrc = (const float2*)(keys + (size_t)b * T * D);
  for (int idx = tid; idx < (T * D) / 2; idx += 512) {   // 6400
    const int t = idx >> 5, f2 = idx & 31;
    const float2 kv = ksrc[idx];
    union { _Float16 h[2]; unsigned u; } pk;
    pk.h[0] = (_Float16)kv.x; pk.h[1] = (_Float16)kv.y;
    *(unsigned*)&ksh[t][f2 * 2] = pk.u;
  }
  __syncthreads();

  const int r = lane & 15, g = lane >> 4;
  float sum[5] = {0.f,0.f,0.f,0.f,0.f}, sq[5] = {0.f,0.f,0.f,0.f,0.f};

  for (int strip = w; strip < 13; strip += 8) {
    const int m0 = strip * 16;
    const f16x8 fa0 = *(const f16x8*)&ksh[m0 + r][g * 8];
    const f16x8 fa1 = *(const f16x8*)&ksh[m0 + r][32 + g * 8];
    #pragma unroll
    for (int n = 0; n < 5; ++n) {
      const f16x8 fb0 = *(const f16x8*)&wsh[n * 16 + r][g * 8];
      const f16x8 fb1 = *(const f16x8*)&wsh[n * 16 + r][32 + g * 8];
      f32x4 c = {0.f, 0.f, 0.f, 0.f};
      c = __builtin_amdgcn_mfma_f32_16x16x32_f16(fa0, fb0, c, 0, 0, 0);
      c = __builtin_amdgcn_mfma_f32_16x16x32_f16(fa1, fb1, c, 0, 0, 0);
      const int col = n * 16 + r;
      const float qv = qtsh[col];
      #pragma unroll
      for (int j = 0; j < 4; ++j) {
        const int row = m0 + g * 4 + j;
        if (row < T) {
          const float o = c[j] + qv;
          z1h[((size_t)b * T + row) * H1 + col] = __float2half(o);
          sum[n] += o; sq[n] += o * o;
        }
      }
    }
  }
  // reduce over the 4 row-groups (lanes l, l+16, l+32, l+48 share col)
  #pragma unroll
  for (int n = 0; n < 5; ++n) {
    float s = sum[n], q2 = sq[n];
    s += __shfl_xor(s, 16);  s += __shfl_xor(s, 32);
    q2 += __shfl_xor(q2, 16); q2 += __shfl_xor(q2, 32);
    if (g == 0) {
      atomicAdd(&bsum[n * 16 + r], s);
      atomicAdd(&bsq[n * 16 + r], q2);
    }
  }
  __syncthreads();
  if (tid < H1) {
    red1p[(size_t)b * 160 + tid]      = bsum[tid];
    red1p[(size_t)b * 160 + H1 + tid] = bsq[tid];
  }
}

// ---------------------------------------------------------------------------
// k_fin: reduce per-block partials -> mean / rstd
// ---------------------------------------------------------------------------
__global__ void k_fin(const float* __restrict__ redp, float* __restrict__ fin,
                      int H, int P)
{
  __shared__ float tmp[160];
  const int tid = threadIdx.x;
  const int S = 2 * H;
  if (tid < S) {
    float s0 = 0.f, s1 = 0.f, s2 = 0.f, s3 = 0.f;
    for (int p = 0; p < P; p += 4) {
      s0 += redp[(size_t)(p + 0) * S + tid];
      s1 += redp[(size_t)(p + 1) * S + tid];
      s2 += redp[(size_t)(p + 2) * S + tid];
      s3 += redp[(size_t)(p + 3) * S + tid];
    }
    tmp[tid] = (s0 + s1) + (s2 + s3);
  }
  __syncthreads();
  if (tid < H) {
    const float n = (float)NROWS;
    const float mean = tmp[tid] / n;
    const float var = tmp[H + tid] / n - mean * mean;
    fin[tid] = mean;
    fin[H + tid] = rsqrtf(var + EPSV);
  }
}

// ---------------------------------------------------------------------------
// k3: h1 = dice1(z1); z2 = h1 @ W2 + b2  via f16 MFMA. 128 rows/block.
// K=80 padded to 96 (zeros), N=40 padded to 48 (masked).
// ---------------------------------------------------------------------------
__global__ __launch_bounds__(512) void k3_z2(
    const __half* __restrict__ z1h, const float* __restrict__ W2,
    const float* __restrict__ b2, const float* __restrict__ a1,
    const float* __restrict__ fin1, __half* __restrict__ z2h,
    float* __restrict__ red2p)
{
  const int blk = blockIdx.x, tid = threadIdx.x;
  const int lane = tid & 63, w = tid >> 6;
  const int r0 = blk * 128;
  __shared__ __align__(16) _Float16 h1sh[128][104];  // 26,624 B (A)
  __shared__ __align__(16) _Float16 w2t[48][104];    //  9,984 B (B^T)
  __shared__ float m1[H1], r1[H1], al1[H1];
  __shared__ float b2sh[48];
  __shared__ float bsum[48], bsq[48];

  if (tid < H1) { m1[tid] = fin1[tid]; r1[tid] = fin1[H1 + tid]; al1[tid] = a1[tid]; }
  if (tid < 48) { b2sh[tid] = (tid < H2) ? b2[tid] : 0.f; bsum[tid] = 0.f; bsq[tid] = 0.f; }
  // zero all of w2t (pad rows/cols), and h1sh pad cols 80..95
  for (int idx = tid; idx < (48 * 104) / 2; idx += 512)   // 2496 u32
    ((unsigned*)w2t)[idx] = 0u;
  for (int idx = tid; idx < 128 * 8; idx += 512) {        // cols 80..95 as 8 u32/row
    const int n = idx >> 3, c = idx & 7;
    *(unsigned*)((char*)&h1sh[n][80] + c * 4) = 0u;
  }
  __syncthreads();

  // fill B^T: w2t[h2][k] = W2[k][h2]  (coalesced over h2)
  for (int idx = tid; idx < H1 * H2; idx += 512) {
    const int k = idx / H2, h2 = idx - k * H2;
    w2t[h2][k] = (_Float16)W2[idx];
  }
  // fill A: dice1 applied to z1h rows r0..r0+127
  const uint2* z1v = (const uint2*)(z1h + (size_t)r0 * H1);
  for (int idx = tid; idx < (128 * H1) / 4; idx += 512) {  // 2560
    const int n = idx / 20, c4 = (idx - n * 20) * 4;
    const uint2 raw = z1v[idx];
    union { uint2 u; __half h[4]; } in; in.u = raw;
    union { _Float16 h[4]; unsigned long long u; } outp;
    #pragma unroll
    for (int j = 0; j < 4; ++j) {
      const int hh = c4 + j;
      const float z = __half2float(in.h[j]);
      outp.h[j] = (_Float16)dice_f(z, m1[hh], r1[hh], al1[hh]);
    }
    *(unsigned long long*)&h1sh[n][c4] = outp.u;
  }
  __syncthreads();

  const int r = lane & 15, g = lane >> 4;
  const int m0 = w * 16;
  const f16x8 fa0 = *(const f16x8*)&h1sh[m0 + r][g * 8];
  const f16x8 fa1 = *(const f16x8*)&h1sh[m0 + r][32 + g * 8];
  const f16x8 fa2 = *(const f16x8*)&h1sh[m0 + r][64 + g * 8];
  float sum[3] = {0.f,0.f,0.f}, sq[3] = {0.f,0.f,0.f};
  #pragma unroll
  for (int n = 0; n < 3; ++n) {
    const f16x8 fb0 = *(const f16x8*)&w2t[n * 16 + r][g * 8];
    const f16x8 fb1 = *(const f16x8*)&w2t[n * 16 + r][32 + g * 8];
    const f16x8 fb2 = *(const f16x8*)&w2t[n * 16 + r][64 + g * 8];
    f32x4 c = {0.f, 0.f, 0.f, 0.f};
    c = __builtin_amdgcn_mfma_f32_16x16x32_f16(fa0, fb0, c, 0, 0, 0);
    c = __builtin_amdgcn_mfma_f32_16x16x32_f16(fa1, fb1, c, 0, 0, 0);
    c = __builtin_amdgcn_mfma_f32_16x16x32_f16(fa2, fb2, c, 0, 0, 0);
    const int col = n * 16 + r;
    if (col < H2) {
      const float bb = b2sh[col];
      #pragma unroll
      for (int j = 0; j < 4; ++j) {
        const int row = m0 + g * 4 + j;
        const float o = c[j] + bb;
        z2h[((size_t)r0 + row) * H2 + col] = __float2half(o);
        sum[n] += o; sq[n] += o * o;
      }
    }
  }
  #pragma unroll
  for (int n = 0; n < 3; ++n) {
    float s = sum[n], q2 = sq[n];
    s += __shfl_xor(s, 16);  s += __shfl_xor(s, 32);
    q2 += __shfl_xor(q2, 16); q2 += __shfl_xor(q2, 32);
    const int col = n * 16 + r;
    if (g == 0 && col < H2) {
      atomicAdd(&bsum[col], s);
      atomicAdd(&bsq[col], q2);
    }
  }
  __syncthreads();
  if (tid < H2) {
    red2p[(size_t)blk * 80 + tid]      = bsum[tid];
    red2p[(size_t)blk * 80 + H2 + tid] = bsq[tid];
  }
}

// ---------------------------------------------------------------------------
// k5: h2 = dice2(z2); scores = h2@W3+b3; mask; softmax; out = w @ keys
// (unchanged from round 2)
// ---------------------------------------------------------------------------
__global__ __launch_bounds__(512, 4) void k5_out(
    const __half* __restrict__ z2h, const float* __restrict__ keys,
    const int* __restrict__ mask, const float* __restrict__ a2,
    const float* __restrict__ fin2, const float* __restrict__ W3,
    const float* __restrict__ b3, float* __restrict__ out)
{
  const int b = blockIdx.x, tid = threadIdx.x;
  __shared__ float h2sh[T][H2 + 1];    // 32,800 B
  __shared__ float w3sh[H2], m2[H2], r2[H2], al2[H2];
  __shared__ float ssh[T];
  __shared__ float red[16];
  __shared__ float osh[8][D];

  if (tid < H2) {
    w3sh[tid] = W3[tid];
    m2[tid] = fin2[tid];
    r2[tid] = fin2[H2 + tid];
    al2[tid] = a2[tid];
  }
  __syncthreads();
  const __half2* z2v = (const __half2*)(z2h + (size_t)b * T * H2);
  for (int idx = tid; idx < (T * H2) / 2; idx += 512) {   // 4000
    const int n = idx / 20, hh = (idx - n * 20) * 2;
    const float2 zf = __half22float2(z2v[idx]);
    h2sh[n][hh]     = dice_f(zf.x, m2[hh],     r2[hh],     al2[hh]);
    h2sh[n][hh + 1] = dice_f(zf.y, m2[hh + 1], r2[hh + 1], al2[hh + 1]);
  }
  __syncthreads();

  float s = -INFINITY;
  if (tid < T) {
    s = b3[0];
    #pragma unroll 8
    for (int f = 0; f < H2; ++f) s = fmaf(h2sh[tid][f], w3sh[f], s);
    if (!mask[b * T + tid]) s = PADV;
  }
  float v = s;
  #pragma unroll
  for (int o = 32; o > 0; o >>= 1) v = fmaxf(v, __shfl_xor(v, o, 64));
  const int lane = tid & 63, wid = tid >> 6;
  if (lane == 0) red[wid] = v;
  __syncthreads();
  float m = red[0];
  #pragma unroll
  for (int w = 1; w < 8; ++w) m = fmaxf(m, red[w]);
  float e = 0.f;
  if (tid < T) { e = expf(s - m); ssh[tid] = e; }
  float v2 = e;
  #pragma unroll
  for (int o = 32; o > 0; o >>= 1) v2 += __shfl_xor(v2, o, 64);
  if (lane == 0) red[8 + wid] = v2;
  __syncthreads();
  float denom = 0.f;
  #pragma unroll
  for (int w = 0; w < 8; ++w) denom += red[8 + w];
  const float inv = 1.f / denom;

  const int dd = tid & 63, tg = tid >> 6;
  float p = 0.f;
  for (int t = tg; t < T; t += 8)
    p = fmaf(ssh[t], keys[((size_t)(b * T) + t) * D + dd], p);
  osh[tg][dd] = p * inv;
  __syncthreads();
  if (tid < D) {
    float o = 0.f;
    #pragma unroll
    for (int w = 0; w < 8; ++w) o += osh[w][tid];
    out[(size_t)b * D + tid] = o;
  }
}

// ---------------------------------------------------------------------------
extern "C" void kernel_launch(void* const* d_in, const int* in_sizes, int n_in,
                              void* d_out, int out_size, void* d_ws, size_t ws_size,
                              hipStream_t stream)
{
  const float* qry  = (const float*)d_in[0];
  const float* keys = (const float*)d_in[1];
  const int*   mask = (const int*)d_in[2];
  const float* W1   = (const float*)d_in[3];
  const float* b1   = (const float*)d_in[4];
  const float* a1   = (const float*)d_in[5];
  const float* W2   = (const float*)d_in[6];
  const float* b2   = (const float*)d_in[7];
  const float* a2   = (const float*)d_in[8];
  const float* W3   = (const float*)d_in[9];
  const float* b3   = (const float*)d_in[10];
  float* out = (float*)d_out;
  char* ws = (char*)d_ws;

  __half* z1h  = (__half*)(ws + Z1H_OFF);
  __half* z2h  = (__half*)(ws + Z2H_OFF);
  float* qt    = (float*)(ws + QT_OFF);
  float* red1p = (float*)(ws + RED1_OFF);
  float* red2p = (float*)(ws + RED2_OFF);
  float* fin1  = (float*)(ws + FIN1_OFF);
  float* fin2  = (float*)(ws + FIN2_OFF);

  k0_qt<<<NB, 128, 0, stream>>>(qry, W1, b1, qt);
  k1_gemm<<<NB, 512, 0, stream>>>(keys, W1, qry, qt, z1h, red1p);
  k_fin<<<1, 256, 0, stream>>>(red1p, fin1, H1, NB);
  k3_z2<<<NROWS / 128, 512, 0, stream>>>(z1h, W2, b2, a1, fin1, z2h, red2p);
  k_fin<<<1, 256, 0, stream>>>(red2p, fin2, H2, NROWS / 128);
  k5_out<<<NB, 512, 0, stream>>>(z2h, keys, mask, a2, fin2, W3, b3, out);
}

// Round 6
// 442.077 us; speedup vs baseline: 1.4562x; 1.4562x over previous
//
#include <hip/hip_runtime.h>
#include <hip/hip_fp16.h>
#include <math.h>

#define NB 2048
#define T 200
#define D 64
#define H1 80
#define H2 40
#define NROWS (NB * T)          // 409600
#define EPSV 1e-8f
#define PADV -4294967295.0f

typedef _Float16 f16x8 __attribute__((ext_vector_type(8)));
typedef float f32x4 __attribute__((ext_vector_type(4)));

// ---- workspace layout (byte offsets) ----
#define Z1H_OFF   0ull                  // __half [NROWS*80]  = 65,536,000 B
#define Z2H_OFF   65536000ull           // __half [NROWS*40]  = 32,768,000 B
#define QT_OFF    98304000ull           // float  [NB*80]     =   655,360 B
#define RED_OFF   98959360ull           // float  [240]: red1[160] | red2[80]
#define FIN1_OFF  98960320ull           // float  [160]
#define FIN2_OFF  98960960ull           // float  [80]

__device__ __forceinline__ float dice_f(float z, float m, float r, float a) {
  const float xn = (z - m) * r;
  const float p = 1.f / (1.f + expf(-xn));
  return z * (p + a * (1.f - p));
}

// ---------------------------------------------------------------------------
// k0: qt[b,h] = b1[h] + sum_f q[f]*(W1a+W1c)[f][h]   (tiny GEMV)
// ---------------------------------------------------------------------------
__global__ __launch_bounds__(128) void k0_qt(
    const float* __restrict__ qry, const float* __restrict__ W1,
    const float* __restrict__ b1, float* __restrict__ qt)
{
  const int b = blockIdx.x, tid = threadIdx.x;
  __shared__ float qsh[D];
  if (tid < D) qsh[tid] = qry[b * D + tid];
  __syncthreads();
  if (tid < H1) {
    float s = b1[tid];
    #pragma unroll 8
    for (int f = 0; f < D; ++f)
      s += qsh[f] * (W1[f * H1 + tid] + W1[(2 * D + f) * H1 + tid]);
    qt[b * H1 + tid] = s;
  }
}

// ---------------------------------------------------------------------------
// k1: z1 = qt[b] + keys[b] @ Weff[b]  via f16 MFMA (f32 accum).
// Stats: LDS partials -> 160 global atomicAdds per block.
// ---------------------------------------------------------------------------
__global__ __launch_bounds__(512) void k1_gemm(
    const float* __restrict__ keys, const float* __restrict__ W1,
    const float* __restrict__ qry, const float* __restrict__ qt,
    __half* __restrict__ z1h, float* __restrict__ red1)
{
  const int b = blockIdx.x, tid = threadIdx.x;
  const int lane = tid & 63, w = tid >> 6;
  __shared__ __align__(16) _Float16 ksh[208][72];   // 29,952 B (A: [t][f])
  __shared__ __align__(16) _Float16 wsh[80][72];    // 11,520 B (B^T: [h][f])
  __shared__ float qsh[D];
  __shared__ float qtsh[H1];
  __shared__ float bsum[H1], bsq[H1];

  if (tid < D) qsh[tid] = qry[b * D + tid];
  if (tid < H1) { qtsh[tid] = qt[b * H1 + tid]; bsum[tid] = 0.f; bsq[tid] = 0.f; }
  __syncthreads();

  // Weff^T[h][f] = W1b - W1c + q[f]*W1d   (coalesced over h)
  for (int idx = tid; idx < D * H1; idx += 512) {
    const int f = idx / H1, h = idx - f * H1;
    const float v = W1[(D + f) * H1 + h] - W1[(2 * D + f) * H1 + h]
                  + qsh[f] * W1[(3 * D + f) * H1 + h];
    wsh[h][f] = (_Float16)v;
  }
  // keys -> f16 LDS
  const float2* ksrc = (const float2*)(keys + (size_t)b * T * D);
  for (int idx = tid; idx < (T * D) / 2; idx += 512) {   // 6400
    const int t = idx >> 5, f2 = idx & 31;
    const float2 kv = ksrc[idx];
    union { _Float16 h[2]; unsigned u; } pk;
    pk.h[0] = (_Float16)kv.x; pk.h[1] = (_Float16)kv.y;
    *(unsigned*)&ksh[t][f2 * 2] = pk.u;
  }
  __syncthreads();

  const int r = lane & 15, g = lane >> 4;
  float sum[5] = {0.f,0.f,0.f,0.f,0.f}, sq[5] = {0.f,0.f,0.f,0.f,0.f};

  for (int strip = w; strip < 13; strip += 8) {
    const int m0 = strip * 16;
    const f16x8 fa0 = *(const f16x8*)&ksh[m0 + r][g * 8];
    const f16x8 fa1 = *(const f16x8*)&ksh[m0 + r][32 + g * 8];
    #pragma unroll
    for (int n = 0; n < 5; ++n) {
      const f16x8 fb0 = *(const f16x8*)&wsh[n * 16 + r][g * 8];
      const f16x8 fb1 = *(const f16x8*)&wsh[n * 16 + r][32 + g * 8];
      f32x4 c = {0.f, 0.f, 0.f, 0.f};
      c = __builtin_amdgcn_mfma_f32_16x16x32_f16(fa0, fb0, c, 0, 0, 0);
      c = __builtin_amdgcn_mfma_f32_16x16x32_f16(fa1, fb1, c, 0, 0, 0);
      const int col = n * 16 + r;
      const float qv = qtsh[col];
      #pragma unroll
      for (int j = 0; j < 4; ++j) {
        const int row = m0 + g * 4 + j;
        if (row < T) {
          const float o = c[j] + qv;
          z1h[((size_t)b * T + row) * H1 + col] = __float2half(o);
          sum[n] += o; sq[n] += o * o;
        }
      }
    }
  }
  // reduce over the 4 row-groups (lanes l, l+16, l+32, l+48 share col)
  #pragma unroll
  for (int n = 0; n < 5; ++n) {
    float s = sum[n], q2 = sq[n];
    s += __shfl_xor(s, 16);  s += __shfl_xor(s, 32);
    q2 += __shfl_xor(q2, 16); q2 += __shfl_xor(q2, 32);
    if (g == 0) {
      atomicAdd(&bsum[n * 16 + r], s);
      atomicAdd(&bsq[n * 16 + r], q2);
    }
  }
  __syncthreads();
  if (tid < H1) {
    atomicAdd(&red1[tid],      bsum[tid]);
    atomicAdd(&red1[H1 + tid], bsq[tid]);
  }
}

// ---------------------------------------------------------------------------
// k_fin: mean / rstd from fully-reduced sum / sumsq (trivial now)
// ---------------------------------------------------------------------------
__global__ void k_fin(const float* __restrict__ red, float* __restrict__ fin, int H)
{
  const int h = threadIdx.x;
  if (h < H) {
    const float n = (float)NROWS;
    const float mean = red[h] / n;
    const float var = red[H + h] / n - mean * mean;
    fin[h] = mean;
    fin[H + h] = rsqrtf(var + EPSV);
  }
}

// ---------------------------------------------------------------------------
// k3: h1 = dice1(z1); z2 = h1 @ W2 + b2  via f16 MFMA. 128 rows/block.
// K=80 padded to 96 (zeros), N=40 padded to 48 (masked).
// ---------------------------------------------------------------------------
__global__ __launch_bounds__(512) void k3_z2(
    const __half* __restrict__ z1h, const float* __restrict__ W2,
    const float* __restrict__ b2, const float* __restrict__ a1,
    const float* __restrict__ fin1, __half* __restrict__ z2h,
    float* __restrict__ red2)
{
  const int blk = blockIdx.x, tid = threadIdx.x;
  const int lane = tid & 63, w = tid >> 6;
  const int r0 = blk * 128;
  __shared__ __align__(16) _Float16 h1sh[128][104];  // 26,624 B (A)
  __shared__ __align__(16) _Float16 w2t[48][104];    //  9,984 B (B^T)
  __shared__ float m1[H1], r1[H1], al1[H1];
  __shared__ float b2sh[48];
  __shared__ float bsum[48], bsq[48];

  if (tid < H1) { m1[tid] = fin1[tid]; r1[tid] = fin1[H1 + tid]; al1[tid] = a1[tid]; }
  if (tid < 48) { b2sh[tid] = (tid < H2) ? b2[tid] : 0.f; bsum[tid] = 0.f; bsq[tid] = 0.f; }
  // zero all of w2t (pad rows/cols), and h1sh pad cols 80..95
  for (int idx = tid; idx < (48 * 104) / 2; idx += 512)   // 2496 u32
    ((unsigned*)w2t)[idx] = 0u;
  for (int idx = tid; idx < 128 * 8; idx += 512) {        // cols 80..95 as 8 u32/row
    const int n = idx >> 3, c = idx & 7;
    *(unsigned*)((char*)&h1sh[n][80] + c * 4) = 0u;
  }
  __syncthreads();

  // fill B^T: w2t[h2][k] = W2[k][h2]  (coalesced over h2)
  for (int idx = tid; idx < H1 * H2; idx += 512) {
    const int k = idx / H2, h2 = idx - k * H2;
    w2t[h2][k] = (_Float16)W2[idx];
  }
  // fill A: dice1 applied to z1h rows r0..r0+127
  const uint2* z1v = (const uint2*)(z1h + (size_t)r0 * H1);
  for (int idx = tid; idx < (128 * H1) / 4; idx += 512) {  // 2560
    const int n = idx / 20, c4 = (idx - n * 20) * 4;
    const uint2 raw = z1v[idx];
    union { uint2 u; __half h[4]; } in; in.u = raw;
    union { _Float16 h[4]; unsigned long long u; } outp;
    #pragma unroll
    for (int j = 0; j < 4; ++j) {
      const int hh = c4 + j;
      const float z = __half2float(in.h[j]);
      outp.h[j] = (_Float16)dice_f(z, m1[hh], r1[hh], al1[hh]);
    }
    *(unsigned long long*)&h1sh[n][c4] = outp.u;
  }
  __syncthreads();

  const int r = lane & 15, g = lane >> 4;
  const int m0 = w * 16;
  const f16x8 fa0 = *(const f16x8*)&h1sh[m0 + r][g * 8];
  const f16x8 fa1 = *(const f16x8*)&h1sh[m0 + r][32 + g * 8];
  const f16x8 fa2 = *(const f16x8*)&h1sh[m0 + r][64 + g * 8];
  float sum[3] = {0.f,0.f,0.f}, sq[3] = {0.f,0.f,0.f};
  #pragma unroll
  for (int n = 0; n < 3; ++n) {
    const f16x8 fb0 = *(const f16x8*)&w2t[n * 16 + r][g * 8];
    const f16x8 fb1 = *(const f16x8*)&w2t[n * 16 + r][32 + g * 8];
    const f16x8 fb2 = *(const f16x8*)&w2t[n * 16 + r][64 + g * 8];
    f32x4 c = {0.f, 0.f, 0.f, 0.f};
    c = __builtin_amdgcn_mfma_f32_16x16x32_f16(fa0, fb0, c, 0, 0, 0);
    c = __builtin_amdgcn_mfma_f32_16x16x32_f16(fa1, fb1, c, 0, 0, 0);
    c = __builtin_amdgcn_mfma_f32_16x16x32_f16(fa2, fb2, c, 0, 0, 0);
    const int col = n * 16 + r;
    if (col < H2) {
      const float bb = b2sh[col];
      #pragma unroll
      for (int j = 0; j < 4; ++j) {
        const int row = m0 + g * 4 + j;
        const float o = c[j] + bb;
        z2h[((size_t)r0 + row) * H2 + col] = __float2half(o);
        sum[n] += o; sq[n] += o * o;
      }
    }
  }
  #pragma unroll
  for (int n = 0; n < 3; ++n) {
    float s = sum[n], q2 = sq[n];
    s += __shfl_xor(s, 16);  s += __shfl_xor(s, 32);
    q2 += __shfl_xor(q2, 16); q2 += __shfl_xor(q2, 32);
    const int col = n * 16 + r;
    if (g == 0 && col < H2) {
      atomicAdd(&bsum[col], s);
      atomicAdd(&bsq[col], q2);
    }
  }
  __syncthreads();
  if (tid < H2) {
    atomicAdd(&red2[tid],      bsum[tid]);
    atomicAdd(&red2[H2 + tid], bsq[tid]);
  }
}

// ---------------------------------------------------------------------------
// k5: h2 = dice2(z2); scores = h2@W3+b3; mask; softmax; out = w @ keys
// ---------------------------------------------------------------------------
__global__ __launch_bounds__(512, 4) void k5_out(
    const __half* __restrict__ z2h, const float* __restrict__ keys,
    const int* __restrict__ mask, const float* __restrict__ a2,
    const float* __restrict__ fin2, const float* __restrict__ W3,
    const float* __restrict__ b3, float* __restrict__ out)
{
  const int b = blockIdx.x, tid = threadIdx.x;
  __shared__ float h2sh[T][H2 + 1];    // 32,800 B
  __shared__ float w3sh[H2], m2[H2], r2[H2], al2[H2];
  __shared__ float ssh[T];
  __shared__ float red[16];
  __shared__ float osh[8][D];

  if (tid < H2) {
    w3sh[tid] = W3[tid];
    m2[tid] = fin2[tid];
    r2[tid] = fin2[H2 + tid];
    al2[tid] = a2[tid];
  }
  __syncthreads();
  const __half2* z2v = (const __half2*)(z2h + (size_t)b * T * H2);
  for (int idx = tid; idx < (T * H2) / 2; idx += 512) {   // 4000
    const int n = idx / 20, hh = (idx - n * 20) * 2;
    const float2 zf = __half22float2(z2v[idx]);
    h2sh[n][hh]     = dice_f(zf.x, m2[hh],     r2[hh],     al2[hh]);
    h2sh[n][hh + 1] = dice_f(zf.y, m2[hh + 1], r2[hh + 1], al2[hh + 1]);
  }
  __syncthreads();

  float s = -INFINITY;
  if (tid < T) {
    s = b3[0];
    #pragma unroll 8
    for (int f = 0; f < H2; ++f) s = fmaf(h2sh[tid][f], w3sh[f], s);
    if (!mask[b * T + tid]) s = PADV;
  }
  float v = s;
  #pragma unroll
  for (int o = 32; o > 0; o >>= 1) v = fmaxf(v, __shfl_xor(v, o, 64));
  const int lane = tid & 63, wid = tid >> 6;
  if (lane == 0) red[wid] = v;
  __syncthreads();
  float m = red[0];
  #pragma unroll
  for (int w = 1; w < 8; ++w) m = fmaxf(m, red[w]);
  float e = 0.f;
  if (tid < T) { e = expf(s - m); ssh[tid] = e; }
  float v2 = e;
  #pragma unroll
  for (int o = 32; o > 0; o >>= 1) v2 += __shfl_xor(v2, o, 64);
  if (lane == 0) red[8 + wid] = v2;
  __syncthreads();
  float denom = 0.f;
  #pragma unroll
  for (int w = 0; w < 8; ++w) denom += red[8 + w];
  const float inv = 1.f / denom;

  const int dd = tid & 63, tg = tid >> 6;
  float p = 0.f;
  for (int t = tg; t < T; t += 8)
    p = fmaf(ssh[t], keys[((size_t)(b * T) + t) * D + dd], p);
  osh[tg][dd] = p * inv;
  __syncthreads();
  if (tid < D) {
    float o = 0.f;
    #pragma unroll
    for (int w = 0; w < 8; ++w) o += osh[w][tid];
    out[(size_t)b * D + tid] = o;
  }
}

// ---------------------------------------------------------------------------
extern "C" void kernel_launch(void* const* d_in, const int* in_sizes, int n_in,
                              void* d_out, int out_size, void* d_ws, size_t ws_size,
                              hipStream_t stream)
{
  const float* qry  = (const float*)d_in[0];
  const float* keys = (const float*)d_in[1];
  const int*   mask = (const int*)d_in[2];
  const float* W1   = (const float*)d_in[3];
  const float* b1   = (const float*)d_in[4];
  const float* a1   = (const float*)d_in[5];
  const float* W2   = (const float*)d_in[6];
  const float* b2   = (const float*)d_in[7];
  const float* a2   = (const float*)d_in[8];
  const float* W3   = (const float*)d_in[9];
  const float* b3   = (const float*)d_in[10];
  float* out = (float*)d_out;
  char* ws = (char*)d_ws;

  __half* z1h = (__half*)(ws + Z1H_OFF);
  __half* z2h = (__half*)(ws + Z2H_OFF);
  float* qt   = (float*)(ws + QT_OFF);
  float* red1 = (float*)(ws + RED_OFF);        // [160]
  float* red2 = (float*)(ws + RED_OFF) + 160;  // [80]
  float* fin1 = (float*)(ws + FIN1_OFF);
  float* fin2 = (float*)(ws + FIN2_OFF);

  hipMemsetAsync(red1, 0, 240 * sizeof(float), stream);

  k0_qt<<<NB, 128, 0, stream>>>(qry, W1, b1, qt);
  k1_gemm<<<NB, 512, 0, stream>>>(keys, W1, qry, qt, z1h, red1);
  k_fin<<<1, 128, 0, stream>>>(red1, fin1, H1);
  k3_z2<<<NROWS / 128, 512, 0, stream>>>(z1h, W2, b2, a1, fin1, z2h, red2);
  k_fin<<<1, 128, 0, stream>>>(red2, fin2, H2);
  k5_out<<<NB, 512, 0, stream>>>(z2h, keys, mask, a2, fin2, W3, b3, out);
}

// Round 7
// 320.301 us; speedup vs baseline: 2.0098x; 1.3802x over previous
//
#include <hip/hip_runtime.h>
#include <hip/hip_fp16.h>
#include <math.h>

#define NB 2048
#define T 200
#define D 64
#define H1 80
#define H2 40
#define NROWS (NB * T)          // 409600
#define NBLK3 (NROWS / 128)     // 3200
#define EPSV 1e-8f
#define PADV -4294967295.0f

typedef _Float16 f16x8 __attribute__((ext_vector_type(8)));
typedef float f32x4 __attribute__((ext_vector_type(4)));

// ---- workspace layout (byte offsets) ----
#define Z1H_OFF   0ull                  // __half [NROWS*80]  = 65,536,000 B
#define Z2H_OFF   65536000ull           // __half [NROWS*40]  = 32,768,000 B
#define QT_OFF    98304000ull           // float  [NB*80]     =   655,360 B
#define RED1_OFF  98959360ull           // float  [NB*160]    = 1,310,720 B
#define RED2_OFF  100270080ull          // float  [3200*80]   = 1,024,000 B
#define FIN1_OFF  101294080ull          // float  [160]
#define FIN2_OFF  101294720ull          // float  [80]

__device__ __forceinline__ float dice_f(float z, float m, float r, float a) {
  const float xn = (z - m) * r;
  const float p = 1.f / (1.f + expf(-xn));
  return z * (p + a * (1.f - p));
}

// ---------------------------------------------------------------------------
// k0: qt[b,h] = b1[h] + sum_f q[f]*(W1a+W1c)[f][h]   (tiny GEMV)
// ---------------------------------------------------------------------------
__global__ __launch_bounds__(128) void k0_qt(
    const float* __restrict__ qry, const float* __restrict__ W1,
    const float* __restrict__ b1, float* __restrict__ qt)
{
  const int b = blockIdx.x, tid = threadIdx.x;
  __shared__ float qsh[D];
  if (tid < D) qsh[tid] = qry[b * D + tid];
  __syncthreads();
  if (tid < H1) {
    float s = b1[tid];
    #pragma unroll 8
    for (int f = 0; f < D; ++f)
      s += qsh[f] * (W1[f * H1 + tid] + W1[(2 * D + f) * H1 + tid]);
    qt[b * H1 + tid] = s;
  }
}

// ---------------------------------------------------------------------------
// k1: z1 = qt[b] + keys[b] @ Weff[b]  via f16 MFMA (f32 accum).
// Stats: LDS partials -> per-block coalesced row write (NO global atomics).
// ---------------------------------------------------------------------------
__global__ __launch_bounds__(512) void k1_gemm(
    const float* __restrict__ keys, const float* __restrict__ W1,
    const float* __restrict__ qry, const float* __restrict__ qt,
    __half* __restrict__ z1h, float* __restrict__ red1p)
{
  const int b = blockIdx.x, tid = threadIdx.x;
  const int lane = tid & 63, w = tid >> 6;
  __shared__ __align__(16) _Float16 ksh[208][72];   // 29,952 B (A: [t][f])
  __shared__ __align__(16) _Float16 wsh[80][72];    // 11,520 B (B^T: [h][f])
  __shared__ float qsh[D];
  __shared__ float qtsh[H1];
  __shared__ float bsum[H1], bsq[H1];

  if (tid < D) qsh[tid] = qry[b * D + tid];
  if (tid < H1) { qtsh[tid] = qt[b * H1 + tid]; bsum[tid] = 0.f; bsq[tid] = 0.f; }
  __syncthreads();

  // Weff^T[h][f] = W1b - W1c + q[f]*W1d   (coalesced over h)
  for (int idx = tid; idx < D * H1; idx += 512) {
    const int f = idx / H1, h = idx - f * H1;
    const float v = W1[(D + f) * H1 + h] - W1[(2 * D + f) * H1 + h]
                  + qsh[f] * W1[(3 * D + f) * H1 + h];
    wsh[h][f] = (_Float16)v;
  }
  // keys -> f16 LDS
  const float2* ksrc = (const float2*)(keys + (size_t)b * T * D);
  for (int idx = tid; idx < (T * D) / 2; idx += 512) {   // 6400
    const int t = idx >> 5, f2 = idx & 31;
    const float2 kv = ksrc[idx];
    union { _Float16 h[2]; unsigned u; } pk;
    pk.h[0] = (_Float16)kv.x; pk.h[1] = (_Float16)kv.y;
    *(unsigned*)&ksh[t][f2 * 2] = pk.u;
  }
  __syncthreads();

  const int r = lane & 15, g = lane >> 4;
  float sum[5] = {0.f,0.f,0.f,0.f,0.f}, sq[5] = {0.f,0.f,0.f,0.f,0.f};

  for (int strip = w; strip < 13; strip += 8) {
    const int m0 = strip * 16;
    const f16x8 fa0 = *(const f16x8*)&ksh[m0 + r][g * 8];
    const f16x8 fa1 = *(const f16x8*)&ksh[m0 + r][32 + g * 8];
    #pragma unroll
    for (int n = 0; n < 5; ++n) {
      const f16x8 fb0 = *(const f16x8*)&wsh[n * 16 + r][g * 8];
      const f16x8 fb1 = *(const f16x8*)&wsh[n * 16 + r][32 + g * 8];
      f32x4 c = {0.f, 0.f, 0.f, 0.f};
      c = __builtin_amdgcn_mfma_f32_16x16x32_f16(fa0, fb0, c, 0, 0, 0);
      c = __builtin_amdgcn_mfma_f32_16x16x32_f16(fa1, fb1, c, 0, 0, 0);
      const int col = n * 16 + r;
      const float qv = qtsh[col];
      #pragma unroll
      for (int j = 0; j < 4; ++j) {
        const int row = m0 + g * 4 + j;
        if (row < T) {
          const float o = c[j] + qv;
          z1h[((size_t)b * T + row) * H1 + col] = __float2half(o);
          sum[n] += o; sq[n] += o * o;
        }
      }
    }
  }
  // reduce over the 4 row-groups (lanes l, l+16, l+32, l+48 share col)
  #pragma unroll
  for (int n = 0; n < 5; ++n) {
    float s = sum[n], q2 = sq[n];
    s += __shfl_xor(s, 16);  s += __shfl_xor(s, 32);
    q2 += __shfl_xor(q2, 16); q2 += __shfl_xor(q2, 32);
    if (g == 0) {
      atomicAdd(&bsum[n * 16 + r], s);
      atomicAdd(&bsq[n * 16 + r], q2);
    }
  }
  __syncthreads();
  if (tid < H1) {
    red1p[(size_t)b * 160 + tid]      = bsum[tid];
    red1p[(size_t)b * 160 + H1 + tid] = bsq[tid];
  }
}

// ---------------------------------------------------------------------------
// k_fin_par: one block per feature h; tree-reduce P partial rows -> mean/rstd
// ---------------------------------------------------------------------------
__global__ __launch_bounds__(256) void k_fin_par(
    const float* __restrict__ redp, float* __restrict__ fin, int H, int P)
{
  const int h = blockIdx.x, tid = threadIdx.x;
  const int S = 2 * H;
  float s = 0.f, q = 0.f;
  for (int p = tid; p < P; p += 256) {
    s += redp[(size_t)p * S + h];
    q += redp[(size_t)p * S + H + h];
  }
  #pragma unroll
  for (int o = 32; o > 0; o >>= 1) { s += __shfl_xor(s, o); q += __shfl_xor(q, o); }
  __shared__ float ssh[4], qsh[4];
  const int wid = tid >> 6;
  if ((tid & 63) == 0) { ssh[wid] = s; qsh[wid] = q; }
  __syncthreads();
  if (tid == 0) {
    const float st = (ssh[0] + ssh[1]) + (ssh[2] + ssh[3]);
    const float qt = (qsh[0] + qsh[1]) + (qsh[2] + qsh[3]);
    const float n = (float)NROWS;
    const float mean = st / n;
    const float var = qt / n - mean * mean;
    fin[h] = mean;
    fin[H + h] = rsqrtf(var + EPSV);
  }
}

// ---------------------------------------------------------------------------
// k3: h1 = dice1(z1); z2 = h1 @ W2 + b2  via f16 MFMA. 128 rows/block.
// K=80 padded to 96 (zeros), N=40 padded to 48 (masked).
// Stats: per-block coalesced row write (NO global atomics).
// ---------------------------------------------------------------------------
__global__ __launch_bounds__(512) void k3_z2(
    const __half* __restrict__ z1h, const float* __restrict__ W2,
    const float* __restrict__ b2, const float* __restrict__ a1,
    const float* __restrict__ fin1, __half* __restrict__ z2h,
    float* __restrict__ red2p)
{
  const int blk = blockIdx.x, tid = threadIdx.x;
  const int lane = tid & 63, w = tid >> 6;
  const int r0 = blk * 128;
  __shared__ __align__(16) _Float16 h1sh[128][104];  // 26,624 B (A)
  __shared__ __align__(16) _Float16 w2t[48][104];    //  9,984 B (B^T)
  __shared__ float m1[H1], r1[H1], al1[H1];
  __shared__ float b2sh[48];
  __shared__ float bsum[48], bsq[48];

  if (tid < H1) { m1[tid] = fin1[tid]; r1[tid] = fin1[H1 + tid]; al1[tid] = a1[tid]; }
  if (tid < 48) { b2sh[tid] = (tid < H2) ? b2[tid] : 0.f; bsum[tid] = 0.f; bsq[tid] = 0.f; }
  // zero all of w2t (pad rows/cols), and h1sh pad cols 80..95
  for (int idx = tid; idx < (48 * 104) / 2; idx += 512)   // 2496 u32
    ((unsigned*)w2t)[idx] = 0u;
  for (int idx = tid; idx < 128 * 8; idx += 512) {        // cols 80..95 as 8 u32/row
    const int n = idx >> 3, c = idx & 7;
    *(unsigned*)((char*)&h1sh[n][80] + c * 4) = 0u;
  }
  __syncthreads();

  // fill B^T: w2t[h2][k] = W2[k][h2]  (coalesced over h2)
  for (int idx = tid; idx < H1 * H2; idx += 512) {
    const int k = idx / H2, h2 = idx - k * H2;
    w2t[h2][k] = (_Float16)W2[idx];
  }
  // fill A: dice1 applied to z1h rows r0..r0+127
  const uint2* z1v = (const uint2*)(z1h + (size_t)r0 * H1);
  for (int idx = tid; idx < (128 * H1) / 4; idx += 512) {  // 2560
    const int n = idx / 20, c4 = (idx - n * 20) * 4;
    const uint2 raw = z1v[idx];
    union { uint2 u; __half h[4]; } in; in.u = raw;
    union { _Float16 h[4]; unsigned long long u; } outp;
    #pragma unroll
    for (int j = 0; j < 4; ++j) {
      const int hh = c4 + j;
      const float z = __half2float(in.h[j]);
      outp.h[j] = (_Float16)dice_f(z, m1[hh], r1[hh], al1[hh]);
    }
    *(unsigned long long*)&h1sh[n][c4] = outp.u;
  }
  __syncthreads();

  const int r = lane & 15, g = lane >> 4;
  const int m0 = w * 16;
  const f16x8 fa0 = *(const f16x8*)&h1sh[m0 + r][g * 8];
  const f16x8 fa1 = *(const f16x8*)&h1sh[m0 + r][32 + g * 8];
  const f16x8 fa2 = *(const f16x8*)&h1sh[m0 + r][64 + g * 8];
  float sum[3] = {0.f,0.f,0.f}, sq[3] = {0.f,0.f,0.f};
  #pragma unroll
  for (int n = 0; n < 3; ++n) {
    const f16x8 fb0 = *(const f16x8*)&w2t[n * 16 + r][g * 8];
    const f16x8 fb1 = *(const f16x8*)&w2t[n * 16 + r][32 + g * 8];
    const f16x8 fb2 = *(const f16x8*)&w2t[n * 16 + r][64 + g * 8];
    f32x4 c = {0.f, 0.f, 0.f, 0.f};
    c = __builtin_amdgcn_mfma_f32_16x16x32_f16(fa0, fb0, c, 0, 0, 0);
    c = __builtin_amdgcn_mfma_f32_16x16x32_f16(fa1, fb1, c, 0, 0, 0);
    c = __builtin_amdgcn_mfma_f32_16x16x32_f16(fa2, fb2, c, 0, 0, 0);
    const int col = n * 16 + r;
    if (col < H2) {
      const float bb = b2sh[col];
      #pragma unroll
      for (int j = 0; j < 4; ++j) {
        const int row = m0 + g * 4 + j;
        const float o = c[j] + bb;
        z2h[((size_t)r0 + row) * H2 + col] = __float2half(o);
        sum[n] += o; sq[n] += o * o;
      }
    }
  }
  #pragma unroll
  for (int n = 0; n < 3; ++n) {
    float s = sum[n], q2 = sq[n];
    s += __shfl_xor(s, 16);  s += __shfl_xor(s, 32);
    q2 += __shfl_xor(q2, 16); q2 += __shfl_xor(q2, 32);
    const int col = n * 16 + r;
    if (g == 0 && col < H2) {
      atomicAdd(&bsum[col], s);
      atomicAdd(&bsq[col], q2);
    }
  }
  __syncthreads();
  if (tid < H2) {
    red2p[(size_t)blk * 80 + tid]      = bsum[tid];
    red2p[(size_t)blk * 80 + H2 + tid] = bsq[tid];
  }
}

// ---------------------------------------------------------------------------
// k5: h2 = dice2(z2); scores = h2@W3+b3; mask; softmax; out = w @ keys
// ---------------------------------------------------------------------------
__global__ __launch_bounds__(512, 4) void k5_out(
    const __half* __restrict__ z2h, const float* __restrict__ keys,
    const int* __restrict__ mask, const float* __restrict__ a2,
    const float* __restrict__ fin2, const float* __restrict__ W3,
    const float* __restrict__ b3, float* __restrict__ out)
{
  const int b = blockIdx.x, tid = threadIdx.x;
  __shared__ float h2sh[T][H2 + 1];    // 32,800 B
  __shared__ float w3sh[H2], m2[H2], r2[H2], al2[H2];
  __shared__ float ssh[T];
  __shared__ float red[16];
  __shared__ float osh[8][D];

  if (tid < H2) {
    w3sh[tid] = W3[tid];
    m2[tid] = fin2[tid];
    r2[tid] = fin2[H2 + tid];
    al2[tid] = a2[tid];
  }
  __syncthreads();
  const __half2* z2v = (const __half2*)(z2h + (size_t)b * T * H2);
  for (int idx = tid; idx < (T * H2) / 2; idx += 512) {   // 4000
    const int n = idx / 20, hh = (idx - n * 20) * 2;
    const float2 zf = __half22float2(z2v[idx]);
    h2sh[n][hh]     = dice_f(zf.x, m2[hh],     r2[hh],     al2[hh]);
    h2sh[n][hh + 1] = dice_f(zf.y, m2[hh + 1], r2[hh + 1], al2[hh + 1]);
  }
  __syncthreads();

  float s = -INFINITY;
  if (tid < T) {
    s = b3[0];
    #pragma unroll 8
    for (int f = 0; f < H2; ++f) s = fmaf(h2sh[tid][f], w3sh[f], s);
    if (!mask[b * T + tid]) s = PADV;
  }
  float v = s;
  #pragma unroll
  for (int o = 32; o > 0; o >>= 1) v = fmaxf(v, __shfl_xor(v, o, 64));
  const int lane = tid & 63, wid = tid >> 6;
  if (lane == 0) red[wid] = v;
  __syncthreads();
  float m = red[0];
  #pragma unroll
  for (int w = 1; w < 8; ++w) m = fmaxf(m, red[w]);
  float e = 0.f;
  if (tid < T) { e = expf(s - m); ssh[tid] = e; }
  float v2 = e;
  #pragma unroll
  for (int o = 32; o > 0; o >>= 1) v2 += __shfl_xor(v2, o, 64);
  if (lane == 0) red[8 + wid] = v2;
  __syncthreads();
  float denom = 0.f;
  #pragma unroll
  for (int w = 0; w < 8; ++w) denom += red[8 + w];
  const float inv = 1.f / denom;

  const int dd = tid & 63, tg = tid >> 6;
  float p = 0.f;
  for (int t = tg; t < T; t += 8)
    p = fmaf(ssh[t], keys[((size_t)(b * T) + t) * D + dd], p);
  osh[tg][dd] = p * inv;
  __syncthreads();
  if (tid < D) {
    float o = 0.f;
    #pragma unroll
    for (int w = 0; w < 8; ++w) o += osh[w][tid];
    out[(size_t)b * D + tid] = o;
  }
}

// ---------------------------------------------------------------------------
extern "C" void kernel_launch(void* const* d_in, const int* in_sizes, int n_in,
                              void* d_out, int out_size, void* d_ws, size_t ws_size,
                              hipStream_t stream)
{
  const float* qry  = (const float*)d_in[0];
  const float* keys = (const float*)d_in[1];
  const int*   mask = (const int*)d_in[2];
  const float* W1   = (const float*)d_in[3];
  const float* b1   = (const float*)d_in[4];
  const float* a1   = (const float*)d_in[5];
  const float* W2   = (const float*)d_in[6];
  const float* b2   = (const float*)d_in[7];
  const float* a2   = (const float*)d_in[8];
  const float* W3   = (const float*)d_in[9];
  const float* b3   = (const float*)d_in[10];
  float* out = (float*)d_out;
  char* ws = (char*)d_ws;

  __half* z1h  = (__half*)(ws + Z1H_OFF);
  __half* z2h  = (__half*)(ws + Z2H_OFF);
  float* qt    = (float*)(ws + QT_OFF);
  float* red1p = (float*)(ws + RED1_OFF);
  float* red2p = (float*)(ws + RED2_OFF);
  float* fin1  = (float*)(ws + FIN1_OFF);
  float* fin2  = (float*)(ws + FIN2_OFF);

  k0_qt<<<NB, 128, 0, stream>>>(qry, W1, b1, qt);
  k1_gemm<<<NB, 512, 0, stream>>>(keys, W1, qry, qt, z1h, red1p);
  k_fin_par<<<H1, 256, 0, stream>>>(red1p, fin1, H1, NB);
  k3_z2<<<NBLK3, 512, 0, stream>>>(z1h, W2, b2, a1, fin1, z2h, red2p);
  k_fin_par<<<H2, 256, 0, stream>>>(red2p, fin2, H2, NBLK3);
  k5_out<<<NB, 512, 0, stream>>>(z2h, keys, mask, a2, fin2, W3, b3, out);
}